// Round 1
// baseline (1135.690 us; speedup 1.0000x reference)
//
#include <hip/hip_runtime.h>
#include <hip/hip_bf16.h>

typedef __attribute__((ext_vector_type(8))) short s16x8;
typedef __attribute__((ext_vector_type(4))) float f32x4;

__device__ __forceinline__ float b2f(unsigned short u) {
  union { unsigned int i; float f; } x; x.i = ((unsigned int)u) << 16; return x.f;
}
__device__ __forceinline__ unsigned short f2b(float f) {
  union { float f; unsigned int i; } x; x.f = f;
  unsigned int r = x.i + 0x7fffu + ((x.i >> 16) & 1u);
  return (unsigned short)(r >> 16);
}

// ---------------- weight packing ----------------
// qkvT[n][c], n in [0,1536): n<512 -> wq head h=n>>6 d=n&63; [512,1024) wk; [1024,1536) wv
__global__ __launch_bounds__(256) void pack_qkv_k(const float* __restrict__ wq,
                                                  const float* __restrict__ wk,
                                                  const float* __restrict__ wv,
                                                  unsigned short* __restrict__ dst) {
  int idx = blockIdx.x * 256 + threadIdx.x;   // n*512 + c
  int n = idx >> 9, c = idx & 511;
  int sel = n >> 9;
  int hn = n & 511;
  const float* src = sel == 0 ? wq : (sel == 1 ? wk : wv);
  float v = src[((hn >> 6) << 15) + (c << 6) + (hn & 63)];  // wq[h][c][d]
  dst[idx] = f2b(v);
}

// dst[n][k] = src[k][n], src is (K,N) row-major
__global__ __launch_bounds__(256) void pack_T_k(const float* __restrict__ src,
                                                unsigned short* __restrict__ dst,
                                                int K, int N) {
  int idx = blockIdx.x * 256 + threadIdx.x;
  int n = idx / K, k = idx % K;
  dst[idx] = f2b(src[(long long)k * N + n]);
}

// ---------------- layernorm (wave per row, C=512) ----------------
__global__ __launch_bounds__(256) void ln_k(const float* __restrict__ in,
                                            const float* __restrict__ g,
                                            const float* __restrict__ bb,
                                            unsigned short* __restrict__ out) {
  int row = blockIdx.x * 4 + (threadIdx.x >> 6);
  int lane = threadIdx.x & 63;
  const float* p = in + (size_t)row * 512 + lane * 8;
  f32x4 a = *(const f32x4*)p;
  f32x4 b = *(const f32x4*)(p + 4);
  float s = a.x + a.y + a.z + a.w + b.x + b.y + b.z + b.w;
  float q = a.x * a.x + a.y * a.y + a.z * a.z + a.w * a.w +
            b.x * b.x + b.y * b.y + b.z * b.z + b.w * b.w;
#pragma unroll
  for (int off = 1; off < 64; off <<= 1) {
    s += __shfl_xor(s, off);
    q += __shfl_xor(q, off);
  }
  float mean = s * (1.0f / 512.0f);
  float rstd = rsqrtf(q * (1.0f / 512.0f) - mean * mean + 1e-5f);
  const float* gp = g + lane * 8;
  const float* bp = bb + lane * 8;
  float vals[8] = {a.x, a.y, a.z, a.w, b.x, b.y, b.z, b.w};
  s16x8 o;
#pragma unroll
  for (int i = 0; i < 8; i++) o[i] = (short)f2b((vals[i] - mean) * rstd * gp[i] + bp[i]);
  *(s16x8*)(out + (size_t)row * 512 + lane * 8) = o;
}

// ---------------- attention (one wave per (b,h); T=16, D=64) ----------------
// qkv: (65536, 1536) bf16 rows = [q | k | v], head h at cols h*64.. within each third.
// o: (65536, 512) bf16, col h*64+d  (heads concatenated in order)
__global__ __launch_bounds__(256) void attn_k(const unsigned short* __restrict__ qkv,
                                              unsigned short* __restrict__ o) {
  int w = (blockIdx.x << 2) + (threadIdx.x >> 6);
  int lane = threadIdx.x & 63;
  int b = w >> 3, h = w & 7;
  int t = lane >> 2, p = lane & 3;   // 4 lanes per query row, 16 d's each

  size_t rowq = (size_t)(b * 16 + t) * 1536 + h * 64 + p * 16;
  float q[16];
  {
    s16x8 q0 = *(const s16x8*)(qkv + rowq);
    s16x8 q1 = *(const s16x8*)(qkv + rowq + 8);
#pragma unroll
    for (int i = 0; i < 8; i++) {
      q[i] = b2f((unsigned short)q0[i]) * 0.125f;       // *= D^-0.5
      q[8 + i] = b2f((unsigned short)q1[i]) * 0.125f;
    }
  }
  float lg[16];
  size_t kbase = (size_t)(b * 16) * 1536 + 512 + h * 64 + p * 16;
#pragma unroll
  for (int s = 0; s < 16; s++) {
    const unsigned short* kp = qkv + kbase + (size_t)s * 1536;
    s16x8 k0 = *(const s16x8*)kp;
    s16x8 k1 = *(const s16x8*)(kp + 8);
    float d = 0.f;
#pragma unroll
    for (int i = 0; i < 8; i++)
      d += q[i] * b2f((unsigned short)k0[i]) + q[8 + i] * b2f((unsigned short)k1[i]);
    d += __shfl_xor(d, 1);
    d += __shfl_xor(d, 2);   // reduce over the 4 d-partitions
    lg[s] = d;
  }
  float mx = -1e30f;
#pragma unroll
  for (int s = 0; s < 16; s++)
    if (s <= t) mx = fmaxf(mx, lg[s]);
  float den = 0.f;
#pragma unroll
  for (int s = 0; s < 16; s++) {
    float e = (s <= t) ? __expf(lg[s] - mx) : 0.f;
    lg[s] = e;
    den += e;
  }
  float inv = 1.f / den;
  float acc[16] = {};
  size_t vbase = kbase + 512;
#pragma unroll
  for (int s = 0; s < 16; s++) {
    const unsigned short* vp = qkv + vbase + (size_t)s * 1536;
    s16x8 v0 = *(const s16x8*)vp;
    s16x8 v1 = *(const s16x8*)(vp + 8);
    float a = lg[s] * inv;
#pragma unroll
    for (int i = 0; i < 8; i++) {
      acc[i] += a * b2f((unsigned short)v0[i]);
      acc[8 + i] += a * b2f((unsigned short)v1[i]);
    }
  }
  size_t orow = (size_t)(b * 16 + t) * 512 + h * 64 + p * 16;
  s16x8 r0, r1;
#pragma unroll
  for (int i = 0; i < 8; i++) {
    r0[i] = (short)f2b(acc[i]);
    r1[i] = (short)f2b(acc[8 + i]);
  }
  *(s16x8*)(o + orow) = r0;
  *(s16x8*)(o + orow + 8) = r1;
}

// ---------------- bf16 MFMA GEMM, B transposed (N x K), 128x128 tile ----------------
enum { EPI_BF16 = 0, EPI_RESF32 = 1, EPI_RELU_BF16 = 2 };

template <int EPI>
__global__ __launch_bounds__(256) void gemm_bt(
    const unsigned short* __restrict__ A,   // (M, K) bf16
    const unsigned short* __restrict__ Bt,  // (N, K) bf16
    int K, int N,
    const float* __restrict__ bias, const float* __restrict__ res,
    float* __restrict__ outF, unsigned short* __restrict__ outB) {
  __shared__ __align__(16) unsigned short As[128 * 40];  // pad 32->40 vs bank conflicts
  __shared__ __align__(16) unsigned short Bs[128 * 40];

  int tid = threadIdx.x;
  int mBase = blockIdx.x * 128;
  int nBase = blockIdx.y * 128;
  int lane = tid & 63;
  int wv = tid >> 6;
  int wr = (wv >> 1) * 64, wc = (wv & 1) * 64;  // 2x2 wave grid, 64x64 each
  int l15 = lane & 15;
  int lk8 = (lane >> 4) * 8;
  int lr4 = (lane >> 4) * 4;

  f32x4 acc[4][4] = {};

  int sr = tid >> 2;          // 0..63
  int sc = (tid & 3) * 8;     // 0,8,16,24
  const unsigned short* pa = A + (size_t)(mBase + sr) * K + sc;
  const unsigned short* pb = Bt + (size_t)(nBase + sr) * K + sc;

  for (int kt = 0; kt < K; kt += 32) {
    __syncthreads();
    s16x8 a0 = *(const s16x8*)(pa + kt);
    s16x8 a1 = *(const s16x8*)(pa + kt + (size_t)64 * K);
    s16x8 b0 = *(const s16x8*)(pb + kt);
    s16x8 b1 = *(const s16x8*)(pb + kt + (size_t)64 * K);
    *(s16x8*)&As[sr * 40 + sc] = a0;
    *(s16x8*)&As[(sr + 64) * 40 + sc] = a1;
    *(s16x8*)&Bs[sr * 40 + sc] = b0;
    *(s16x8*)&Bs[(sr + 64) * 40 + sc] = b1;
    __syncthreads();
    s16x8 af[4], bf[4];
#pragma unroll
    for (int m = 0; m < 4; m++) af[m] = *(const s16x8*)&As[(wr + m * 16 + l15) * 40 + lk8];
#pragma unroll
    for (int n = 0; n < 4; n++) bf[n] = *(const s16x8*)&Bs[(wc + n * 16 + l15) * 40 + lk8];
#pragma unroll
    for (int m = 0; m < 4; m++)
#pragma unroll
      for (int n = 0; n < 4; n++)
        acc[m][n] = __builtin_amdgcn_mfma_f32_16x16x32_bf16(af[m], bf[n], acc[m][n], 0, 0, 0);
  }

#pragma unroll
  for (int n = 0; n < 4; n++) {
    int gc = nBase + wc + n * 16 + l15;
    float bv = (EPI == EPI_BF16) ? 0.f : bias[gc];
#pragma unroll
    for (int m = 0; m < 4; m++) {
#pragma unroll
      for (int j = 0; j < 4; j++) {
        int gr = mBase + wr + m * 16 + lr4 + j;
        size_t off = (size_t)gr * N + gc;
        float v = acc[m][n][j] + bv;
        if (EPI == EPI_RESF32)
          outF[off] = v + res[off];
        else if (EPI == EPI_RELU_BF16)
          outB[off] = f2b(fmaxf(v, 0.f));
        else
          outB[off] = f2b(v);
      }
    }
  }
}

// ---------------- launch ----------------
extern "C" void kernel_launch(void* const* d_in, const int* in_sizes, int n_in,
                              void* d_out, int out_size, void* d_ws, size_t ws_size,
                              hipStream_t stream) {
  const float* x      = (const float*)d_in[0];
  const float* ln1_g  = (const float*)d_in[1];
  const float* ln1_b  = (const float*)d_in[2];
  const float* wq     = (const float*)d_in[3];
  const float* wk     = (const float*)d_in[4];
  const float* wv     = (const float*)d_in[5];
  const float* w_proj = (const float*)d_in[6];
  const float* b_proj = (const float*)d_in[7];
  const float* ln2_g  = (const float*)d_in[8];
  const float* ln2_b  = (const float*)d_in[9];
  const float* w1     = (const float*)d_in[10];
  const float* b1     = (const float*)d_in[11];
  const float* w2     = (const float*)d_in[12];
  const float* b2     = (const float*)d_in[13];
  float* out = (float*)d_out;

  char* ws = (char*)d_ws;
  unsigned short* qkvT  = (unsigned short*)(ws + 0);          // 1536*512*2  = 1,572,864
  unsigned short* projT = (unsigned short*)(ws + 1572864);    // 512*512*2   =   524,288
  unsigned short* w1T   = (unsigned short*)(ws + 2097152);    // 2048*512*2  = 2,097,152
  unsigned short* w2T   = (unsigned short*)(ws + 4194304);    // 512*2048*2  = 2,097,152
  unsigned short* hbuf  = (unsigned short*)(ws + 6291456);    // 65536*512*2 = 67,108,864 (h, then h2)
  unsigned short* qkv   = (unsigned short*)(ws + 73400320);   // 65536*1536*2; reused as ff (65536*2048*2)
  unsigned short* obuf  = (unsigned short*)(ws + 341835776);  // 65536*512*2
  // total ws use: ~409 MB.  y (fp32) lives in d_out.

  pack_qkv_k<<<3072, 256, 0, stream>>>(wq, wk, wv, qkvT);
  pack_T_k<<<1024, 256, 0, stream>>>(w_proj, projT, 512, 512);
  pack_T_k<<<4096, 256, 0, stream>>>(w1, w1T, 512, 2048);
  pack_T_k<<<4096, 256, 0, stream>>>(w2, w2T, 2048, 512);

  ln_k<<<16384, 256, 0, stream>>>(x, ln1_g, ln1_b, hbuf);

  // qkv = h @ [wq|wk|wv]  (M=65536, K=512, N=1536)
  gemm_bt<EPI_BF16><<<dim3(512, 12), 256, 0, stream>>>(hbuf, qkvT, 512, 1536,
                                                       nullptr, nullptr, nullptr, qkv);
  attn_k<<<8192, 256, 0, stream>>>(qkv, obuf);

  // y = o @ w_proj + b_proj + x   -> d_out (fp32)
  gemm_bt<EPI_RESF32><<<dim3(512, 4), 256, 0, stream>>>(obuf, projT, 512, 512,
                                                        b_proj, x, out, nullptr);
  // h2 = LN2(y)
  ln_k<<<16384, 256, 0, stream>>>(out, ln2_g, ln2_b, hbuf);

  // ff = relu(h2 @ w1 + b1)  (N=2048)
  unsigned short* ff = qkv;
  gemm_bt<EPI_RELU_BF16><<<dim3(512, 16), 256, 0, stream>>>(hbuf, w1T, 512, 2048,
                                                            b1, nullptr, nullptr, ff);
  // out = ff @ w2 + b2 + y   (K=2048, N=512)
  gemm_bt<EPI_RESF32><<<dim3(512, 4), 256, 0, stream>>>(ff, w2T, 2048, 512,
                                                        b2, out, out, nullptr);
}

// Round 2
// 955.913 us; speedup vs baseline: 1.1881x; 1.1881x over previous
//
#include <hip/hip_runtime.h>
#include <hip/hip_bf16.h>

typedef __attribute__((ext_vector_type(8))) short s16x8;
typedef __attribute__((ext_vector_type(4))) float f32x4;

#define GAS __attribute__((address_space(1)))
#define LAS __attribute__((address_space(3)))

__device__ __forceinline__ float b2f(unsigned short u) {
  union { unsigned int i; float f; } x; x.i = ((unsigned int)u) << 16; return x.f;
}
__device__ __forceinline__ unsigned short f2b(float f) {
  union { float f; unsigned int i; } x; x.f = f;
  unsigned int r = x.i + 0x7fffu + ((x.i >> 16) & 1u);
  return (unsigned short)(r >> 16);
}

// async global->LDS, 16B per lane; lds dest is wave-uniform base + lane*16
__device__ __forceinline__ void gl16(const unsigned short* g, unsigned short* l) {
  __builtin_amdgcn_global_load_lds((const GAS unsigned int*)g,
                                   (LAS unsigned int*)l, 16, 0, 0);
}

// ---------------- weight packing ----------------
__global__ __launch_bounds__(256) void pack_qkv_k(const float* __restrict__ wq,
                                                  const float* __restrict__ wk,
                                                  const float* __restrict__ wv,
                                                  unsigned short* __restrict__ dst) {
  int idx = blockIdx.x * 256 + threadIdx.x;   // n*512 + c
  int n = idx >> 9, c = idx & 511;
  int sel = n >> 9;
  int hn = n & 511;
  const float* src = sel == 0 ? wq : (sel == 1 ? wk : wv);
  float v = src[((hn >> 6) << 15) + (c << 6) + (hn & 63)];  // wq[h][c][d]
  dst[idx] = f2b(v);
}

// dst[n][k] = src[k][n], src is (K,N) row-major
__global__ __launch_bounds__(256) void pack_T_k(const float* __restrict__ src,
                                                unsigned short* __restrict__ dst,
                                                int K, int N) {
  int idx = blockIdx.x * 256 + threadIdx.x;
  int n = idx / K, k = idx % K;
  dst[idx] = f2b(src[(long long)k * N + n]);
}

// ---------------- layernorm (wave per row, C=512) ----------------
__global__ __launch_bounds__(256) void ln_k(const float* __restrict__ in,
                                            const float* __restrict__ g,
                                            const float* __restrict__ bb,
                                            unsigned short* __restrict__ out) {
  int row = blockIdx.x * 4 + (threadIdx.x >> 6);
  int lane = threadIdx.x & 63;
  const float* p = in + (size_t)row * 512 + lane * 8;
  f32x4 a = *(const f32x4*)p;
  f32x4 b = *(const f32x4*)(p + 4);
  float s = a.x + a.y + a.z + a.w + b.x + b.y + b.z + b.w;
  float q = a.x * a.x + a.y * a.y + a.z * a.z + a.w * a.w +
            b.x * b.x + b.y * b.y + b.z * b.z + b.w * b.w;
#pragma unroll
  for (int off = 1; off < 64; off <<= 1) {
    s += __shfl_xor(s, off);
    q += __shfl_xor(q, off);
  }
  float mean = s * (1.0f / 512.0f);
  float rstd = rsqrtf(q * (1.0f / 512.0f) - mean * mean + 1e-5f);
  const float* gp = g + lane * 8;
  const float* bp = bb + lane * 8;
  float vals[8] = {a.x, a.y, a.z, a.w, b.x, b.y, b.z, b.w};
  s16x8 o;
#pragma unroll
  for (int i = 0; i < 8; i++) o[i] = (short)f2b((vals[i] - mean) * rstd * gp[i] + bp[i]);
  *(s16x8*)(out + (size_t)row * 512 + lane * 8) = o;
}

// ---------------- attention (one wave per (b,h); T=16, D=64) ----------------
__global__ __launch_bounds__(256) void attn_k(const unsigned short* __restrict__ qkv,
                                              unsigned short* __restrict__ o) {
  int w = (blockIdx.x << 2) + (threadIdx.x >> 6);
  int lane = threadIdx.x & 63;
  int b = w >> 3, h = w & 7;
  int t = lane >> 2, p = lane & 3;   // 4 lanes per query row, 16 d's each

  size_t rowq = (size_t)(b * 16 + t) * 1536 + h * 64 + p * 16;
  float q[16];
  {
    s16x8 q0 = *(const s16x8*)(qkv + rowq);
    s16x8 q1 = *(const s16x8*)(qkv + rowq + 8);
#pragma unroll
    for (int i = 0; i < 8; i++) {
      q[i] = b2f((unsigned short)q0[i]) * 0.125f;
      q[8 + i] = b2f((unsigned short)q1[i]) * 0.125f;
    }
  }
  float lg[16];
  size_t kbase = (size_t)(b * 16) * 1536 + 512 + h * 64 + p * 16;
#pragma unroll
  for (int s = 0; s < 16; s++) {
    const unsigned short* kp = qkv + kbase + (size_t)s * 1536;
    s16x8 k0 = *(const s16x8*)kp;
    s16x8 k1 = *(const s16x8*)(kp + 8);
    float d = 0.f;
#pragma unroll
    for (int i = 0; i < 8; i++)
      d += q[i] * b2f((unsigned short)k0[i]) + q[8 + i] * b2f((unsigned short)k1[i]);
    d += __shfl_xor(d, 1);
    d += __shfl_xor(d, 2);
    lg[s] = d;
  }
  float mx = -1e30f;
#pragma unroll
  for (int s = 0; s < 16; s++)
    if (s <= t) mx = fmaxf(mx, lg[s]);
  float den = 0.f;
#pragma unroll
  for (int s = 0; s < 16; s++) {
    float e = (s <= t) ? __expf(lg[s] - mx) : 0.f;
    lg[s] = e;
    den += e;
  }
  float inv = 1.f / den;
  float acc[16] = {};
  size_t vbase = kbase + 512;
#pragma unroll
  for (int s = 0; s < 16; s++) {
    const unsigned short* vp = qkv + vbase + (size_t)s * 1536;
    s16x8 v0 = *(const s16x8*)vp;
    s16x8 v1 = *(const s16x8*)(vp + 8);
    float a = lg[s] * inv;
#pragma unroll
    for (int i = 0; i < 8; i++) {
      acc[i] += a * b2f((unsigned short)v0[i]);
      acc[8 + i] += a * b2f((unsigned short)v1[i]);
    }
  }
  size_t orow = (size_t)(b * 16 + t) * 512 + h * 64 + p * 16;
  s16x8 r0, r1;
#pragma unroll
  for (int i = 0; i < 8; i++) {
    r0[i] = (short)f2b(acc[i]);
    r1[i] = (short)f2b(acc[8 + i]);
  }
  *(s16x8*)(o + orow) = r0;
  *(s16x8*)(o + orow + 8) = r1;
}

// ---------------- bf16 MFMA GEMM (m97 structure), B transposed (N x K) ----------------
// 128x128 tile, BK=32, 4 waves. Linear LDS [128][32] staged via global_load_lds
// width 16. Bank-conflict fix: 16B-slot XOR swizzle p = s ^ ((row>>1)&3),
// applied on the global SOURCE address (LDS dest linear, rule #21) and on the
// ds_read address. Grid is 1D, N-fastest tile order, XCD-chunked swizzle.
enum { EPI_BF16 = 0, EPI_RESF32 = 1, EPI_RELU_BF16 = 2 };

template <int EPI>
__global__ __launch_bounds__(256) void gemm_bt(
    const unsigned short* __restrict__ A,   // (M, K) bf16
    const unsigned short* __restrict__ Bt,  // (N, K) bf16
    int K, int N, int nT,
    const float* __restrict__ bias, const float* __restrict__ res,
    float* __restrict__ outF, unsigned short* __restrict__ outB) {
  __shared__ __align__(16) unsigned short As[128 * 32];
  __shared__ __align__(16) unsigned short Bs[128 * 32];

  int tid = threadIdx.x;
  // XCD-chunked (each XCD gets a contiguous run of logical ids), N-fastest
  int lid = ((int)blockIdx.x & 7) * ((int)gridDim.x >> 3) + ((int)blockIdx.x >> 3);
  int mBase = (lid / nT) * 128;
  int nBase = (lid % nT) * 128;

  int lane = tid & 63;
  int wv = tid >> 6;
  int wr = (wv >> 1) * 64, wc = (wv & 1) * 64;  // 2x2 wave grid, 64x64 each
  int l15 = lane & 15;
  int lr4 = (lane >> 4) * 4;
  // swizzled fragment column (elements): logical slot = lane>>4, row bits from l15
  int fc = (((lane >> 4) ^ ((l15 >> 1) & 3)) << 3);

  // staging: thread tid covers LDS row sr, physical slot tid&3; source column
  // is the swizzled logical slot so LDS[row][p] = global[row][p ^ ((row>>1)&3)]
  int sr = tid >> 2;
  int gc = (((tid & 3) ^ ((tid >> 3) & 3)) << 3);
  const unsigned short* pa = A + (size_t)(mBase + sr) * K + gc;
  const unsigned short* pb = Bt + (size_t)(nBase + sr) * K + gc;
  unsigned short* lA = As + wv * 512;   // wave-uniform LDS bases (1024 B/wave)
  unsigned short* lB = Bs + wv * 512;
  size_t rowskip = (size_t)64 * K;

  f32x4 acc[4][4] = {};

  for (int kt = 0; kt < K; kt += 32) {
    __syncthreads();                       // previous iteration's reads done
    gl16(pa + kt, lA);                     // rows 0..63
    gl16(pa + kt + rowskip, lA + 2048);    // rows 64..127
    gl16(pb + kt, lB);
    gl16(pb + kt + rowskip, lB + 2048);
    __syncthreads();                       // compiler drains vmcnt(0) before barrier
    s16x8 af[4], bf[4];
#pragma unroll
    for (int m = 0; m < 4; m++) af[m] = *(const s16x8*)&As[(wr + m * 16 + l15) * 32 + fc];
#pragma unroll
    for (int n = 0; n < 4; n++) bf[n] = *(const s16x8*)&Bs[(wc + n * 16 + l15) * 32 + fc];
#pragma unroll
    for (int m = 0; m < 4; m++)
#pragma unroll
      for (int n = 0; n < 4; n++)
        acc[m][n] = __builtin_amdgcn_mfma_f32_16x16x32_bf16(af[m], bf[n], acc[m][n], 0, 0, 0);
  }

#pragma unroll
  for (int n = 0; n < 4; n++) {
    int gc2 = nBase + wc + n * 16 + l15;
    float bv = (EPI == EPI_BF16) ? 0.f : bias[gc2];
#pragma unroll
    for (int m = 0; m < 4; m++) {
#pragma unroll
      for (int j = 0; j < 4; j++) {
        int gr = mBase + wr + m * 16 + lr4 + j;
        size_t off = (size_t)gr * N + gc2;
        float v = acc[m][n][j] + bv;
        if (EPI == EPI_RESF32)
          outF[off] = v + res[off];
        else if (EPI == EPI_RELU_BF16)
          outB[off] = f2b(fmaxf(v, 0.f));
        else
          outB[off] = f2b(v);
      }
    }
  }
}

// ---------------- launch ----------------
extern "C" void kernel_launch(void* const* d_in, const int* in_sizes, int n_in,
                              void* d_out, int out_size, void* d_ws, size_t ws_size,
                              hipStream_t stream) {
  const float* x      = (const float*)d_in[0];
  const float* ln1_g  = (const float*)d_in[1];
  const float* ln1_b  = (const float*)d_in[2];
  const float* wq     = (const float*)d_in[3];
  const float* wk     = (const float*)d_in[4];
  const float* wv     = (const float*)d_in[5];
  const float* w_proj = (const float*)d_in[6];
  const float* b_proj = (const float*)d_in[7];
  const float* ln2_g  = (const float*)d_in[8];
  const float* ln2_b  = (const float*)d_in[9];
  const float* w1     = (const float*)d_in[10];
  const float* b1     = (const float*)d_in[11];
  const float* w2     = (const float*)d_in[12];
  const float* b2     = (const float*)d_in[13];
  float* out = (float*)d_out;

  char* ws = (char*)d_ws;
  unsigned short* qkvT  = (unsigned short*)(ws + 0);          // 1536*512*2
  unsigned short* projT = (unsigned short*)(ws + 1572864);    // 512*512*2
  unsigned short* w1T   = (unsigned short*)(ws + 2097152);    // 2048*512*2
  unsigned short* w2T   = (unsigned short*)(ws + 4194304);    // 512*2048*2
  unsigned short* hbuf  = (unsigned short*)(ws + 6291456);    // 65536*512*2 (h, then h2)
  unsigned short* qkv   = (unsigned short*)(ws + 73400320);   // 65536*1536*2; reused as ff
  unsigned short* obuf  = (unsigned short*)(ws + 341835776);  // 65536*512*2

  pack_qkv_k<<<3072, 256, 0, stream>>>(wq, wk, wv, qkvT);
  pack_T_k<<<1024, 256, 0, stream>>>(w_proj, projT, 512, 512);
  pack_T_k<<<4096, 256, 0, stream>>>(w1, w1T, 512, 2048);
  pack_T_k<<<4096, 256, 0, stream>>>(w2, w2T, 2048, 512);

  ln_k<<<16384, 256, 0, stream>>>(x, ln1_g, ln1_b, hbuf);

  // qkv = h @ [wq|wk|wv]  (M=65536, K=512, N=1536)  grid 512*12 = 6144
  gemm_bt<EPI_BF16><<<6144, 256, 0, stream>>>(hbuf, qkvT, 512, 1536, 12,
                                              nullptr, nullptr, nullptr, qkv);
  attn_k<<<8192, 256, 0, stream>>>(qkv, obuf);

  // y = o @ w_proj + b_proj + x   -> d_out (fp32)   grid 512*4 = 2048
  gemm_bt<EPI_RESF32><<<2048, 256, 0, stream>>>(obuf, projT, 512, 512, 4,
                                                b_proj, x, out, nullptr);
  // h2 = LN2(y)
  ln_k<<<16384, 256, 0, stream>>>(out, ln2_g, ln2_b, hbuf);

  // ff = relu(h2 @ w1 + b1)  (N=2048)  grid 512*16 = 8192
  unsigned short* ff = qkv;
  gemm_bt<EPI_RELU_BF16><<<8192, 256, 0, stream>>>(hbuf, w1T, 512, 2048, 16,
                                                   b1, nullptr, nullptr, ff);
  // out = ff @ w2 + b2 + y   (K=2048, N=512)  grid 512*4 = 2048
  gemm_bt<EPI_RESF32><<<2048, 256, 0, stream>>>(ff, w2T, 2048, 512, 4,
                                                b2, out, out, nullptr);
}

// Round 3
// 891.332 us; speedup vs baseline: 1.2741x; 1.0725x over previous
//
#include <hip/hip_runtime.h>
#include <hip/hip_bf16.h>

typedef __attribute__((ext_vector_type(8))) short s16x8;
typedef __attribute__((ext_vector_type(4))) float f32x4;

#define GAS __attribute__((address_space(1)))
#define LAS __attribute__((address_space(3)))

__device__ __forceinline__ float b2f(unsigned short u) {
  union { unsigned int i; float f; } x; x.i = ((unsigned int)u) << 16; return x.f;
}
__device__ __forceinline__ unsigned short f2b(float f) {
  union { float f; unsigned int i; } x; x.f = f;
  unsigned int r = x.i + 0x7fffu + ((x.i >> 16) & 1u);
  return (unsigned short)(r >> 16);
}

// async global->LDS, 16B per lane; lds dest is wave-uniform base + lane*16
__device__ __forceinline__ void gl16(const unsigned short* g, unsigned short* l) {
  __builtin_amdgcn_global_load_lds((const GAS unsigned int*)g,
                                   (LAS unsigned int*)l, 16, 0, 0);
}

// ---------------- weight packing ----------------
__global__ __launch_bounds__(256) void pack_qkv_k(const float* __restrict__ wq,
                                                  const float* __restrict__ wk,
                                                  const float* __restrict__ wv,
                                                  unsigned short* __restrict__ dst) {
  int idx = blockIdx.x * 256 + threadIdx.x;   // n*512 + c
  int n = idx >> 9, c = idx & 511;
  int sel = n >> 9;
  int hn = n & 511;
  const float* src = sel == 0 ? wq : (sel == 1 ? wk : wv);
  float v = src[((hn >> 6) << 15) + (c << 6) + (hn & 63)];  // wq[h][c][d]
  dst[idx] = f2b(v);
}

// dst[n][k] = src[k][n], src is (K,N) row-major
__global__ __launch_bounds__(256) void pack_T_k(const float* __restrict__ src,
                                                unsigned short* __restrict__ dst,
                                                int K, int N) {
  int idx = blockIdx.x * 256 + threadIdx.x;
  int n = idx / K, k = idx % K;
  dst[idx] = f2b(src[(long long)k * N + n]);
}

// ---------------- layernorm (wave per row, C=512), fp32 input ----------------
__global__ __launch_bounds__(256) void ln_k(const float* __restrict__ in,
                                            const float* __restrict__ g,
                                            const float* __restrict__ bb,
                                            unsigned short* __restrict__ out) {
  int row = blockIdx.x * 4 + (threadIdx.x >> 6);
  int lane = threadIdx.x & 63;
  const float* p = in + (size_t)row * 512 + lane * 8;
  f32x4 a = *(const f32x4*)p;
  f32x4 b = *(const f32x4*)(p + 4);
  float vals[8] = {a.x, a.y, a.z, a.w, b.x, b.y, b.z, b.w};
  float s = 0.f, q = 0.f;
#pragma unroll
  for (int i = 0; i < 8; i++) { s += vals[i]; q += vals[i] * vals[i]; }
#pragma unroll
  for (int off = 1; off < 64; off <<= 1) {
    s += __shfl_xor(s, off);
    q += __shfl_xor(q, off);
  }
  float mean = s * (1.0f / 512.0f);
  float rstd = rsqrtf(q * (1.0f / 512.0f) - mean * mean + 1e-5f);
  const float* gp = g + lane * 8;
  const float* bp = bb + lane * 8;
  s16x8 o;
#pragma unroll
  for (int i = 0; i < 8; i++) o[i] = (short)f2b((vals[i] - mean) * rstd * gp[i] + bp[i]);
  *(s16x8*)(out + (size_t)row * 512 + lane * 8) = o;
}

// ---------------- layernorm, bf16 input ----------------
__global__ __launch_bounds__(256) void ln_b_k(const unsigned short* __restrict__ in,
                                              const float* __restrict__ g,
                                              const float* __restrict__ bb,
                                              unsigned short* __restrict__ out) {
  int row = blockIdx.x * 4 + (threadIdx.x >> 6);
  int lane = threadIdx.x & 63;
  s16x8 v8 = *(const s16x8*)(in + (size_t)row * 512 + lane * 8);
  float vals[8];
#pragma unroll
  for (int i = 0; i < 8; i++) vals[i] = b2f((unsigned short)v8[i]);
  float s = 0.f, q = 0.f;
#pragma unroll
  for (int i = 0; i < 8; i++) { s += vals[i]; q += vals[i] * vals[i]; }
#pragma unroll
  for (int off = 1; off < 64; off <<= 1) {
    s += __shfl_xor(s, off);
    q += __shfl_xor(q, off);
  }
  float mean = s * (1.0f / 512.0f);
  float rstd = rsqrtf(q * (1.0f / 512.0f) - mean * mean + 1e-5f);
  const float* gp = g + lane * 8;
  const float* bp = bb + lane * 8;
  s16x8 o;
#pragma unroll
  for (int i = 0; i < 8; i++) o[i] = (short)f2b((vals[i] - mean) * rstd * gp[i] + bp[i]);
  *(s16x8*)(out + (size_t)row * 512 + lane * 8) = o;
}

// ---------------- attention (one wave per (b,h); T=16, D=64) ----------------
__global__ __launch_bounds__(256) void attn_k(const unsigned short* __restrict__ qkv,
                                              unsigned short* __restrict__ o) {
  int w = (blockIdx.x << 2) + (threadIdx.x >> 6);
  int lane = threadIdx.x & 63;
  int b = w >> 3, h = w & 7;
  int t = lane >> 2, p = lane & 3;   // 4 lanes per query row, 16 d's each

  size_t rowq = (size_t)(b * 16 + t) * 1536 + h * 64 + p * 16;
  float q[16];
  {
    s16x8 q0 = *(const s16x8*)(qkv + rowq);
    s16x8 q1 = *(const s16x8*)(qkv + rowq + 8);
#pragma unroll
    for (int i = 0; i < 8; i++) {
      q[i] = b2f((unsigned short)q0[i]) * 0.125f;
      q[8 + i] = b2f((unsigned short)q1[i]) * 0.125f;
    }
  }
  float lg[16];
  size_t kbase = (size_t)(b * 16) * 1536 + 512 + h * 64 + p * 16;
#pragma unroll
  for (int s = 0; s < 16; s++) {
    const unsigned short* kp = qkv + kbase + (size_t)s * 1536;
    s16x8 k0 = *(const s16x8*)kp;
    s16x8 k1 = *(const s16x8*)(kp + 8);
    float d = 0.f;
#pragma unroll
    for (int i = 0; i < 8; i++)
      d += q[i] * b2f((unsigned short)k0[i]) + q[8 + i] * b2f((unsigned short)k1[i]);
    d += __shfl_xor(d, 1);
    d += __shfl_xor(d, 2);
    lg[s] = d;
  }
  float mx = -1e30f;
#pragma unroll
  for (int s = 0; s < 16; s++)
    if (s <= t) mx = fmaxf(mx, lg[s]);
  float den = 0.f;
#pragma unroll
  for (int s = 0; s < 16; s++) {
    float e = (s <= t) ? __expf(lg[s] - mx) : 0.f;
    lg[s] = e;
    den += e;
  }
  float inv = 1.f / den;
  float acc[16] = {};
  size_t vbase = kbase + 512;
#pragma unroll
  for (int s = 0; s < 16; s++) {
    const unsigned short* vp = qkv + vbase + (size_t)s * 1536;
    s16x8 v0 = *(const s16x8*)vp;
    s16x8 v1 = *(const s16x8*)(vp + 8);
    float a = lg[s] * inv;
#pragma unroll
    for (int i = 0; i < 8; i++) {
      acc[i] += a * b2f((unsigned short)v0[i]);
      acc[8 + i] += a * b2f((unsigned short)v1[i]);
    }
  }
  size_t orow = (size_t)(b * 16 + t) * 512 + h * 64 + p * 16;
  s16x8 r0, r1;
#pragma unroll
  for (int i = 0; i < 8; i++) {
    r0[i] = (short)f2b(acc[i]);
    r1[i] = (short)f2b(acc[8 + i]);
  }
  *(s16x8*)(o + orow) = r0;
  *(s16x8*)(o + orow + 8) = r1;
}

// ---------------- bf16 MFMA GEMM, double-buffered 2-phase pipeline ----------------
// 128x128 tile, BK=32, 4 waves. Linear LDS staged via global_load_lds width 16,
// both-sides XOR swizzle p = s ^ ((row>>1)&3) (verified 0 bank conflicts).
// 2-phase: STAGE(next buf) issued BEFORE compute(cur); single __syncthreads per
// tile drains vmcnt after compute -> HBM latency hides under MFMA phase (T3).
enum { EPI_BF16 = 0, EPI_RESF32 = 1, EPI_RELU_BF16 = 2, EPI_YB = 3, EPI_OUTB = 4 };

template <int EPI>
__global__ __launch_bounds__(256) void gemm_bt(
    const unsigned short* __restrict__ A,   // (M, K) bf16
    const unsigned short* __restrict__ Bt,  // (N, K) bf16
    int K, int N, int nT,
    const float* __restrict__ bias, const void* __restrict__ res,
    float* __restrict__ outF, unsigned short* __restrict__ outB) {
  __shared__ __align__(16) unsigned short As[2][128 * 32];
  __shared__ __align__(16) unsigned short Bs[2][128 * 32];

  int tid = threadIdx.x;
  // XCD-chunked 1D swizzle, N-fastest tile order (grids are multiples of 8)
  int lid = ((int)blockIdx.x & 7) * ((int)gridDim.x >> 3) + ((int)blockIdx.x >> 3);
  int mBase = (lid / nT) * 128;
  int nBase = (lid % nT) * 128;

  int lane = tid & 63;
  int wv = tid >> 6;
  int wr = (wv >> 1) * 64, wc = (wv & 1) * 64;  // 2x2 wave grid, 64x64 each
  int l15 = lane & 15;
  int lr4 = (lane >> 4) * 4;
  int fc = (((lane >> 4) ^ ((l15 >> 1) & 3)) << 3);  // swizzled fragment column

  // staging: thread covers LDS row sr, physical slot tid&3; global source col
  // pre-swizzled so LDS[row][p] = global[row][p ^ ((row>>1)&3)]
  int sr = tid >> 2;
  int gc = (((tid & 3) ^ ((tid >> 3) & 3)) << 3);
  const unsigned short* pa = A + (size_t)(mBase + sr) * K + gc;
  const unsigned short* pb = Bt + (size_t)(nBase + sr) * K + gc;
  size_t rowskip = (size_t)64 * K;

  f32x4 acc[4][4] = {};

  auto stage = [&](int b, int kt) {
    unsigned short* lA = &As[b][wv * 512];  // wave-uniform base + lane*16B
    unsigned short* lB = &Bs[b][wv * 512];
    gl16(pa + kt, lA);
    gl16(pa + kt + rowskip, lA + 2048);
    gl16(pb + kt, lB);
    gl16(pb + kt + rowskip, lB + 2048);
  };

  stage(0, 0);
  __syncthreads();  // vmcnt(0) drain + barrier: buf0 ready
  int cur = 0;
  for (int kt = 0; kt < K; kt += 32) {
    if (kt + 32 < K) stage(cur ^ 1, kt + 32);  // prefetch next tile (in flight)
    s16x8 af[4], bf[4];
#pragma unroll
    for (int m = 0; m < 4; m++)
      af[m] = *(const s16x8*)&As[cur][(wr + m * 16 + l15) * 32 + fc];
#pragma unroll
    for (int n = 0; n < 4; n++)
      bf[n] = *(const s16x8*)&Bs[cur][(wc + n * 16 + l15) * 32 + fc];
#pragma unroll
    for (int m = 0; m < 4; m++)
#pragma unroll
      for (int n = 0; n < 4; n++)
        acc[m][n] = __builtin_amdgcn_mfma_f32_16x16x32_bf16(af[m], bf[n], acc[m][n], 0, 0, 0);
    __syncthreads();  // drains prefetch vmcnt AFTER compute; all waves done reading cur
    cur ^= 1;
  }

#pragma unroll
  for (int n = 0; n < 4; n++) {
    int gc2 = nBase + wc + n * 16 + l15;
    float bv = (EPI == EPI_BF16) ? 0.f : bias[gc2];
#pragma unroll
    for (int m = 0; m < 4; m++) {
#pragma unroll
      for (int j = 0; j < 4; j++) {
        int gr = mBase + wr + m * 16 + lr4 + j;
        size_t off = (size_t)gr * N + gc2;
        float v = acc[m][n][j] + bv;
        if (EPI == EPI_RESF32)
          outF[off] = v + ((const float*)res)[off];
        else if (EPI == EPI_YB)
          outB[off] = f2b(v + ((const float*)res)[off]);
        else if (EPI == EPI_OUTB)
          outF[off] = v + b2f(((const unsigned short*)res)[off]);
        else if (EPI == EPI_RELU_BF16)
          outB[off] = f2b(fmaxf(v, 0.f));
        else
          outB[off] = f2b(v);
      }
    }
  }
}

// ---------------- launch ----------------
extern "C" void kernel_launch(void* const* d_in, const int* in_sizes, int n_in,
                              void* d_out, int out_size, void* d_ws, size_t ws_size,
                              hipStream_t stream) {
  const float* x      = (const float*)d_in[0];
  const float* ln1_g  = (const float*)d_in[1];
  const float* ln1_b  = (const float*)d_in[2];
  const float* wq     = (const float*)d_in[3];
  const float* wk     = (const float*)d_in[4];
  const float* wv     = (const float*)d_in[5];
  const float* w_proj = (const float*)d_in[6];
  const float* b_proj = (const float*)d_in[7];
  const float* ln2_g  = (const float*)d_in[8];
  const float* ln2_b  = (const float*)d_in[9];
  const float* w1     = (const float*)d_in[10];
  const float* b1     = (const float*)d_in[11];
  const float* w2     = (const float*)d_in[12];
  const float* b2     = (const float*)d_in[13];
  float* out = (float*)d_out;

  char* ws = (char*)d_ws;
  unsigned short* qkvT  = (unsigned short*)(ws + 0);          // 1.5 MB
  unsigned short* projT = (unsigned short*)(ws + 1572864);    // 0.5 MB
  unsigned short* w1T   = (unsigned short*)(ws + 2097152);    // 2 MB
  unsigned short* w2T   = (unsigned short*)(ws + 4194304);    // 2 MB
  unsigned short* hbuf  = (unsigned short*)(ws + 6291456);    // 67 MB (h, then h2)
  unsigned short* qkv   = (unsigned short*)(ws + 73400320);   // 201 MB; reused as ff (268 MB)
  unsigned short* obuf  = (unsigned short*)(ws + 341835776);  // 67 MB
  unsigned short* ybuf  = (unsigned short*)(ws + 408944640);  // 67 MB (bf16 y) if room
  bool yb16 = ws_size >= 476053504ull;

  pack_qkv_k<<<3072, 256, 0, stream>>>(wq, wk, wv, qkvT);
  pack_T_k<<<1024, 256, 0, stream>>>(w_proj, projT, 512, 512);
  pack_T_k<<<4096, 256, 0, stream>>>(w1, w1T, 512, 2048);
  pack_T_k<<<4096, 256, 0, stream>>>(w2, w2T, 2048, 512);

  ln_k<<<16384, 256, 0, stream>>>(x, ln1_g, ln1_b, hbuf);

  // qkv = h @ [wq|wk|wv]  (M=65536, K=512, N=1536)
  gemm_bt<EPI_BF16><<<6144, 256, 0, stream>>>(hbuf, qkvT, 512, 1536, 12,
                                              nullptr, nullptr, nullptr, qkv);
  attn_k<<<8192, 256, 0, stream>>>(qkv, obuf);

  unsigned short* ff = qkv;  // qkv dead after attn
  if (yb16) {
    // y(bf16) = o @ w_proj + b_proj + x
    gemm_bt<EPI_YB><<<2048, 256, 0, stream>>>(obuf, projT, 512, 512, 4,
                                              b_proj, x, nullptr, ybuf);
    ln_b_k<<<16384, 256, 0, stream>>>(ybuf, ln2_g, ln2_b, hbuf);
    gemm_bt<EPI_RELU_BF16><<<8192, 256, 0, stream>>>(hbuf, w1T, 512, 2048, 16,
                                                     b1, nullptr, nullptr, ff);
    // out(f32) = ff @ w2 + b2 + y(bf16)
    gemm_bt<EPI_OUTB><<<2048, 256, 0, stream>>>(ff, w2T, 2048, 512, 4,
                                                b2, ybuf, out, nullptr);
  } else {
    // fallback: y fp32 in d_out
    gemm_bt<EPI_RESF32><<<2048, 256, 0, stream>>>(obuf, projT, 512, 512, 4,
                                                  b_proj, x, out, nullptr);
    ln_k<<<16384, 256, 0, stream>>>(out, ln2_g, ln2_b, hbuf);
    gemm_bt<EPI_RELU_BF16><<<8192, 256, 0, stream>>>(hbuf, w1T, 512, 2048, 16,
                                                     b1, nullptr, nullptr, ff);
    gemm_bt<EPI_RESF32><<<2048, 256, 0, stream>>>(ff, w2T, 2048, 512, 4,
                                                  b2, out, out, nullptr);
  }
}